// Round 12
// baseline (214.588 us; speedup 1.0000x reference)
//
#include <hip/hip_runtime.h>
#include <hip/hip_bf16.h>
#include <math.h>

typedef short bf16x8 __attribute__((ext_vector_type(8)));
typedef float f32x16 __attribute__((ext_vector_type(16)));

constexpr int CIN = 32, COUT = 64, D = 16, H = 32, W = 32;

// ---------------- ws layout ----------------
// [0, 884736) : wtp bf16 [cls8][t27][co64][ci32]
constexpr size_t WS_NEED = 884736u;

// Per-wave item lists: item = (cls, alpha), code = cls + alpha*8.
static __device__ const unsigned char IT_CODE[24] = {
    0, 8, 16, 3,                  // w0 (93 taps)
    1, 9, 17, 11, 19, 7,          // w1 (86)
    2, 10, 18, 5, 13, 21, 15,     // w2 (98)
    4, 12, 20, 6, 14, 22, 23};    // w3 (98)
static __device__ const unsigned char IT_START[5] = {0, 4, 10, 17, 24};

// Coalesced weight pack: block = (ci*64+co), lane k in [0,125).
// kd = pd + 2*td bijective: pd=kd&1, td=kd>>1. Only valid taps are written;
// invalid (cls,t) slots are never read by main_k.
__global__ void prep_w(const float* __restrict__ w, unsigned short* __restrict__ wtp) {
    int pair = blockIdx.x;              // ci*64 + co, 2048 blocks
    int k = threadIdx.x;                // 128 threads
    if (k >= 125) return;
    int ci = pair >> 6, co = pair & 63;
    float v = w[(size_t)pair * 125 + k];
    int kd = k / 25, kh = (k / 5) % 5, kw = k % 5;
    int pd = kd & 1, td = kd >> 1;
    int ph = kh & 1, th = kh >> 1;
    int pw = kw & 1, tw = kw >> 1;
    int cls = pd * 4 + ph * 2 + pw;
    int t   = td * 9 + th * 3 + tw;
    __hip_bfloat16 b = __float2bfloat16(v);
    wtp[((cls * 27 + t) * 64 + co) * 32 + ci] = *reinterpret_cast<unsigned short*>(&b);
}

__global__ __launch_bounds__(256, 2) void main_k(
    const unsigned short* __restrict__ wtp, const float* __restrict__ x,
    const float* __restrict__ bias, float* __restrict__ out)
{
    __shared__ unsigned short Xs[25600];   // 51200 B, granule-XOR swizzled
    int bx = blockIdx.x;                   // (n*5+d0)*10 + h0, 800 total
    int h0 = bx % 10;
    int d0 = (bx / 10) % 5;
    int n  = bx / 50;
    int tid = threadIdx.x;

    // ---- stage Xs directly from x (fp32 -> bf16, transpose, swizzle) ----
    // logical Xs[p25][ww32][ci32]; iw = ww-1; phys granule = (ci>>3)^((ww>>1)&3)
    int id0 = 3 * d0 - 1, ih0 = 3 * h0 - 1;
    for (int u = tid; u < 6400; u += 256) {
        int q  = u & 7;
        int ci = (u >> 3) & 31;
        int p  = u >> 8;
        int dd = p / 5, hl = p % 5;
        int id = id0 + dd, ih = ih0 + hl;
        float4 v = {0.f, 0.f, 0.f, 0.f};
        if (id >= 0 && ih >= 0)
            v = ((const float4*)(x + (((size_t)(n * CIN + ci) * D + id) * H + ih) * W))[q];
        unsigned short hj[4];
        {
            __hip_bfloat16 b0 = __float2bfloat16(v.x); hj[0] = *reinterpret_cast<unsigned short*>(&b0);
            __hip_bfloat16 b1 = __float2bfloat16(v.y); hj[1] = *reinterpret_cast<unsigned short*>(&b1);
            __hip_bfloat16 b2 = __float2bfloat16(v.z); hj[2] = *reinterpret_cast<unsigned short*>(&b2);
            __hip_bfloat16 b3 = __float2bfloat16(v.w); hj[3] = *reinterpret_cast<unsigned short*>(&b3);
        }
        int rowb = p * 1024;
        int cig = ci >> 3, cil = ci & 7;
#pragma unroll
        for (int j = 0; j < 4; ++j) {
            int ww = 4 * q + 1 + j;
            if (ww < 32)
                Xs[rowb + ww * 32 + ((cig ^ ((ww >> 1) & 3)) << 3) + cil] = hj[j];
        }
        if (q == 0)
            Xs[rowb + (cig << 3) + cil] = 0;   // ww=0 (iw=-1) zero pad
    }

    int lane = tid & 63, wv = tid >> 6;
    int l31 = lane & 31, hh2 = lane >> 5;   // hh2 = k/row half
    int wv_s = __builtin_amdgcn_readfirstlane(wv);

    // B lane offset (bytes) into tap tile [co64][ci32]: co=nh*32+l31, ci=f*16+hh2*8
    int laneB = l31 * 64 + hh2 * 16;
    // A lane offsets (bytes): row R = min(l31,29)+s, granule (2f+hh2)^((R>>1)&3)
    int m_c = l31 > 29 ? 29 : l31;
    int lp[3][2];
#pragma unroll
    for (int s = 0; s < 3; ++s)
#pragma unroll
        for (int f = 0; f < 2; ++f) {
            int R = m_c + s;
            lp[s][f] = R * 64 + (((2 * f + hh2) ^ ((R >> 1) & 3)) << 4);
        }

    f32x16 mx[2];
#pragma unroll
    for (int nh = 0; nh < 2; ++nh)
#pragma unroll
        for (int r = 0; r < 16; ++r) mx[nh][r] = -INFINITY;

    __syncthreads();
    const char* xsb = (const char*)Xs;

    int it0 = IT_START[wv_s], it1 = IT_START[wv_s + 1];
#pragma unroll 1
    for (int ii = it0; ii < it1; ++ii) {
        int code  = __builtin_amdgcn_readfirstlane(IT_CODE[ii]);
        int cls   = code & 7;
        int alpha = code >> 3;
        int ntd = 3 - ((cls >> 2) & 1), nth = 3 - ((cls >> 1) & 1), ntw = 3 - (cls & 1);
        const char* tbb = (const char*)wtp + (size_t)cls * 27 * 4096 + laneB;
        const int T = ntd * nth * ntw;   // >= 8

        f32x16 acc[3][2];
#pragma unroll
        for (int b = 0; b < 3; ++b)
#pragma unroll
            for (int nh = 0; nh < 2; ++nh)
#pragma unroll
                for (int r = 0; r < 16; ++r) acc[b][nh][r] = 0.f;

        int ptd = 0, pth = 0, ptw = 0;
        auto adv = [&]() {
            ++ptw;
            if (ptw == ntw) { ptw = 0; ++pth; if (pth == nth) { pth = 0; ++ptd; } }
        };

        // ---- prologue: load A+B for tap 0 (E), ss = 2 ----
        bf16x8 bE00, bE01, bE10, bE11, aE[3][2];
        {
            bE00 = *(const bf16x8*)(tbb);
            bE01 = *(const bf16x8*)(tbb + 32);
            bE10 = *(const bf16x8*)(tbb + 2048);
            bE11 = *(const bf16x8*)(tbb + 2080);
            const char* rb = xsb + ((alpha + 2) * 5 + 2) * 2048;
#pragma unroll
            for (int b = 0; b < 3; ++b) {
                aE[b][0] = *(const bf16x8*)(rb + b * 2048 + lp[2][0]);
                aE[b][1] = *(const bf16x8*)(rb + b * 2048 + lp[2][1]);
            }
        }
        adv();
        // ---- load A+B for tap 1 (O) ----
        bf16x8 bO00, bO01, bO10, bO11, aO[3][2];
        {
            const char* bq = tbb + (ptd * 9 + pth * 3 + ptw) * 4096;
            bO00 = *(const bf16x8*)(bq);
            bO01 = *(const bf16x8*)(bq + 32);
            bO10 = *(const bf16x8*)(bq + 2048);
            bO11 = *(const bf16x8*)(bq + 2080);
            int ss = 2 - ptw;
            int lpa0 = ss == 0 ? lp[0][0] : (ss == 1 ? lp[1][0] : lp[2][0]);
            int lpa1 = ss == 0 ? lp[0][1] : (ss == 1 ? lp[1][1] : lp[2][1]);
            const char* rb = xsb + ((alpha + 2 - ptd) * 5 + (2 - pth)) * 2048;
#pragma unroll
            for (int b = 0; b < 3; ++b) {
                aO[b][0] = *(const bf16x8*)(rb + b * 2048 + lpa0);
                aO[b][1] = *(const bf16x8*)(rb + b * 2048 + lpa1);
            }
        }
        adv();

#pragma unroll 1
        for (int it = 0; it < T; it += 2) {
            // ---- consume E ----
#pragma unroll
            for (int b = 0; b < 3; ++b) {
                acc[b][0] = __builtin_amdgcn_mfma_f32_32x32x16_bf16(aE[b][0], bE00, acc[b][0], 0, 0, 0);
                acc[b][1] = __builtin_amdgcn_mfma_f32_32x32x16_bf16(aE[b][0], bE10, acc[b][1], 0, 0, 0);
            }
#pragma unroll
            for (int b = 0; b < 3; ++b) {
                acc[b][0] = __builtin_amdgcn_mfma_f32_32x32x16_bf16(aE[b][1], bE01, acc[b][0], 0, 0, 0);
                acc[b][1] = __builtin_amdgcn_mfma_f32_32x32x16_bf16(aE[b][1], bE11, acc[b][1], 0, 0, 0);
            }
            if (it + 2 < T) {     // re-issue E for tap it+2
                const char* bq = tbb + (ptd * 9 + pth * 3 + ptw) * 4096;
                bE00 = *(const bf16x8*)(bq);
                bE01 = *(const bf16x8*)(bq + 32);
                bE10 = *(const bf16x8*)(bq + 2048);
                bE11 = *(const bf16x8*)(bq + 2080);
                int ss = 2 - ptw;
                int lpa0 = ss == 0 ? lp[0][0] : (ss == 1 ? lp[1][0] : lp[2][0]);
                int lpa1 = ss == 0 ? lp[0][1] : (ss == 1 ? lp[1][1] : lp[2][1]);
                const char* rb = xsb + ((alpha + 2 - ptd) * 5 + (2 - pth)) * 2048;
#pragma unroll
                for (int b = 0; b < 3; ++b) {
                    aE[b][0] = *(const bf16x8*)(rb + b * 2048 + lpa0);
                    aE[b][1] = *(const bf16x8*)(rb + b * 2048 + lpa1);
                }
                adv();
            }
            if (it + 1 < T) {
                // ---- consume O ----
#pragma unroll
                for (int b = 0; b < 3; ++b) {
                    acc[b][0] = __builtin_amdgcn_mfma_f32_32x32x16_bf16(aO[b][0], bO00, acc[b][0], 0, 0, 0);
                    acc[b][1] = __builtin_amdgcn_mfma_f32_32x32x16_bf16(aO[b][0], bO10, acc[b][1], 0, 0, 0);
                }
#pragma unroll
                for (int b = 0; b < 3; ++b) {
                    acc[b][0] = __builtin_amdgcn_mfma_f32_32x32x16_bf16(aO[b][1], bO01, acc[b][0], 0, 0, 0);
                    acc[b][1] = __builtin_amdgcn_mfma_f32_32x32x16_bf16(aO[b][1], bO11, acc[b][1], 0, 0, 0);
                }
                if (it + 3 < T) {   // re-issue O for tap it+3
                    const char* bq = tbb + (ptd * 9 + pth * 3 + ptw) * 4096;
                    bO00 = *(const bf16x8*)(bq);
                    bO01 = *(const bf16x8*)(bq + 32);
                    bO10 = *(const bf16x8*)(bq + 2048);
                    bO11 = *(const bf16x8*)(bq + 2080);
                    int ss = 2 - ptw;
                    int lpa0 = ss == 0 ? lp[0][0] : (ss == 1 ? lp[1][0] : lp[2][0]);
                    int lpa1 = ss == 0 ? lp[0][1] : (ss == 1 ? lp[1][1] : lp[2][1]);
                    const char* rb = xsb + ((alpha + 2 - ptd) * 5 + (2 - pth)) * 2048;
#pragma unroll
                    for (int b = 0; b < 3; ++b) {
                        aO[b][0] = *(const bf16x8*)(rb + b * 2048 + lpa0);
                        aO[b][1] = *(const bf16x8*)(rb + b * 2048 + lpa1);
                    }
                    adv();
                }
            }
        }

        // fold item into running max
#pragma unroll
        for (int nh = 0; nh < 2; ++nh)
#pragma unroll
            for (int r = 0; r < 16; ++r) {
                float m = fmaxf(fmaxf(acc[0][nh][r], acc[1][nh][r]), acc[2][nh][r]);
                mx[nh][r] = fmaxf(mx[nh][r], m);
            }
    }

    // ---- epilogue ----
    // C/D row = (r&3) + 8*(r>>2) + 4*hh2 ; col co = nh*32 + l31 ; window = row/3.
    // rows 30,31 (hh2=1, r=14,15) are clamped dups -> excluded.
    __syncthreads();                 // Xs reads done; reuse as epi buffer
    float* epi = (float*)Xs;         // [(wv*2+hh2)*10 + win][co64]
#pragma unroll
    for (int nh = 0; nh < 2; ++nh) {
        float wp[10];
#pragma unroll
        for (int i = 0; i < 10; ++i) wp[i] = -INFINITY;
        const f32x16& v = mx[nh];
        if (hh2 == 0) {
            wp[0] = fmaxf(fmaxf(v[0], v[1]), v[2]);
            wp[1] = v[3];
            wp[2] = v[4];
            wp[3] = fmaxf(fmaxf(v[5], v[6]), v[7]);
            wp[5] = fmaxf(v[8], v[9]);
            wp[6] = fmaxf(v[10], v[11]);
            wp[8] = fmaxf(fmaxf(v[12], v[13]), v[14]);
            wp[9] = v[15];
        } else {
            wp[1] = fmaxf(v[0], v[1]);
            wp[2] = fmaxf(v[2], v[3]);
            wp[4] = fmaxf(fmaxf(v[4], v[5]), v[6]);
            wp[5] = v[7];
            wp[6] = v[8];
            wp[7] = fmaxf(fmaxf(v[9], v[10]), v[11]);
            wp[9] = fmaxf(v[12], v[13]);
        }
        int col = nh * 32 + l31;
#pragma unroll
        for (int win = 0; win < 10; ++win)
            epi[((wv * 2 + hh2) * 10 + win) * 64 + col] = wp[win];
    }
    __syncthreads();

    int elemBase = ((n * 5 + d0) * 10 + h0) * 10;
    float bco = bias[lane];
#pragma unroll 1
    for (int win = wv_s; win < 10; win += 4) {
        float v = -INFINITY;
#pragma unroll
        for (int src = 0; src < 8; ++src)
            v = fmaxf(v, epi[(src * 10 + win) * 64 + lane]);
        v += bco;
#pragma unroll
        for (int off = 32; off > 0; off >>= 1) v += __shfl_xor(v, off);
        if (lane == 0) out[elemBase + win] = v;
    }
}

// ---------------- fallback (round-1 kernel, no ws needed) ----------------
__global__ __launch_bounds__(256) void fused_fallback(
    const float* __restrict__ x, const float* __restrict__ wsrc,
    const float* __restrict__ bias, float* __restrict__ out)
{
    __shared__ float xs[CIN * 125];
    __shared__ float wmax[4][64];
    const int b  = blockIdx.x;
    const int w0 = b % 10, h0 = (b / 10) % 10, d0 = (b / 100) % 5, n = b / 500;
    const int tid = threadIdx.x;
    const int id0 = 3 * d0 - 1, ih0 = 3 * h0 - 1, iw0 = 3 * w0 - 1;
    for (int e = tid; e < CIN * 125; e += 256) {
        int kk = e % 5, jj = (e / 5) % 5, ii = (e / 25) % 5, c = e / 125;
        int id = id0 + ii, ih = ih0 + jj, iw = iw0 + kk;
        float v = 0.f;
        if (id >= 0 && ih >= 0 && iw >= 0)
            v = x[(((n * CIN + c) * D + id) * H + ih) * W + iw];
        xs[e] = v;
    }
    __syncthreads();
    const int lane = tid & 63, wv = tid >> 6;
    float lmax = -INFINITY;
    for (int ccls = 0; ccls < 2; ++ccls) {
        const int cls = wv * 2 + ccls;
        const int pd = (cls >> 2) & 1, ph = (cls >> 1) & 1, pw = cls & 1;
        float acc[27];
#pragma unroll
        for (int i = 0; i < 27; ++i) acc[i] = 0.f;
        for (int ci = 0; ci < CIN; ++ci) {
            float wr[27];
#pragma unroll
            for (int t = 0; t < 27; ++t) {
                int td = t / 9, th = (t / 3) % 3, tw = t % 3;
                int kd = pd + 2 * td, kh = ph + 2 * th, kw = pw + 2 * tw;
                wr[t] = (kd < 5 && kh < 5 && kw < 5)
                          ? wsrc[((ci * 64 + lane) * 125) + kd * 25 + kh * 5 + kw] : 0.f;
            }
            const float* xb = xs + ci * 125;
#pragma unroll
            for (int td = 0; td < 3; ++td)
#pragma unroll
            for (int th = 0; th < 3; ++th)
#pragma unroll
            for (int tw = 0; tw < 3; ++tw) {
                const float wval = wr[(td * 3 + th) * 3 + tw];
#pragma unroll
                for (int a = 0; a < 3; ++a)
#pragma unroll
                for (int bb = 0; bb < 3; ++bb)
#pragma unroll
                for (int cc = 0; cc < 3; ++cc)
                    acc[(a * 3 + bb) * 3 + cc] +=
                        xb[(a + 2 - td) * 25 + (bb + 2 - th) * 5 + (cc + 2 - tw)] * wval;
            }
        }
#pragma unroll
        for (int i = 0; i < 27; ++i) lmax = fmaxf(lmax, acc[i]);
    }
    wmax[wv][lane] = lmax;
    __syncthreads();
    if (wv == 0) {
        float m = fmaxf(fmaxf(wmax[0][lane], wmax[1][lane]),
                        fmaxf(wmax[2][lane], wmax[3][lane]));
        m += bias[lane];
        for (int off = 32; off > 0; off >>= 1) m += __shfl_down(m, off);
        if (lane == 0) out[b] = m;
    }
}

extern "C" void kernel_launch(void* const* d_in, const int* in_sizes, int n_in,
                              void* d_out, int out_size, void* d_ws, size_t ws_size,
                              hipStream_t stream) {
    const float* x    = (const float*)d_in[0];
    const float* w    = (const float*)d_in[1];
    const float* bias = (const float*)d_in[2];
    float* out = (float*)d_out;

    if (ws_size >= WS_NEED) {
        unsigned short* wtp = (unsigned short*)d_ws;
        prep_w<<<2048, 128, 0, stream>>>(w, wtp);
        main_k<<<800, 256, 0, stream>>>(wtp, x, bias, out);
    } else {
        fused_fallback<<<8000, 256, 0, stream>>>(x, w, bias, out);
    }
}